// Round 1
// baseline (1363.831 us; speedup 1.0000x reference)
//
#include <hip/hip_runtime.h>

#define DEV __device__ __forceinline__

typedef short bf16x8 __attribute__((ext_vector_type(8)));
typedef float f32x4 __attribute__((ext_vector_type(4)));

#define S_TOT 2304
#define D3    3072
#define NLONG 2048

DEV unsigned short f2b(float f) {
    union { float f; unsigned u; } v; v.f = f;
    unsigned r = v.u + 0x7fffu + ((v.u >> 16) & 1u);
    return (unsigned short)(r >> 16);
}
DEV float b2f(unsigned short u) {
    union { unsigned u; float f; } v; v.u = ((unsigned)u) << 16;
    return v.f;
}

#define GLL16(g, l) __builtin_amdgcn_global_load_lds( \
    (const __attribute__((address_space(1))) void*)(g), \
    (__attribute__((address_space(3))) void*)(l), 16, 0, 0)

// ---------------- casts ----------------
__global__ __launch_bounds__(256) void k_cast(const float* __restrict__ in,
                                              unsigned short* __restrict__ out, long n) {
    long i = ((long)blockIdx.x * 256 + threadIdx.x) * 4;
    long stride = (long)gridDim.x * 1024;
    for (; i < n; i += stride) {
        float4 v = *(const float4*)(in + i);
        ushort4 o = make_ushort4(f2b(v.x), f2b(v.y), f2b(v.z), f2b(v.w));
        *(ushort4*)(out + i) = o;
    }
}

__global__ __launch_bounds__(256) void k_castcopy(const float* __restrict__ in,
                                                  float* __restrict__ outf,
                                                  unsigned short* __restrict__ outb, long n) {
    long i = ((long)blockIdx.x * 256 + threadIdx.x) * 4;
    long stride = (long)gridDim.x * 1024;
    for (; i < n; i += stride) {
        float4 v = *(const float4*)(in + i);
        *(float4*)(outf + i) = v;
        ushort4 o = make_ushort4(f2b(v.x), f2b(v.y), f2b(v.z), f2b(v.w));
        *(ushort4*)(outb + i) = o;
    }
}

// ---------------- GEMM: C[M,N] = A[M,K] @ B[N,K]^T + bias ----------------
// m97 structure: 128x128 tile, BK=32, 4 waves (each 64x64), global_load_lds w=16.
template<int OBF, int RELU>
__global__ __launch_bounds__(256, 2) void k_gemm(const unsigned short* __restrict__ A,
                                                 const unsigned short* __restrict__ B,
                                                 const float* __restrict__ bias,
                                                 float* __restrict__ Cf,
                                                 unsigned short* __restrict__ Cb,
                                                 int M, int N, int K) {
    __shared__ unsigned short As[128 * 32];
    __shared__ unsigned short Bs[128 * 32];
    const int tid  = threadIdx.x;
    const int lane = tid & 63;
    const int wave = tid >> 6;
    const int g = lane >> 4, li = lane & 15;
    const int bm = blockIdx.x, bn = blockIdx.y;
    const int wm = (wave >> 1) * 64, wn = (wave & 1) * 64;

    f32x4 acc[4][4] = {};

    const long abase = (long)bm * 128 * K;
    const long bbase = (long)bn * 128 * K;
    const int srow = tid >> 2;            // slot row (tid part)
    const int scol = (tid & 3) * 8;       // 8 bf16 per 16B slot

    for (int kt = 0; kt < K; kt += 32) {
#pragma unroll
        for (int r = 0; r < 2; ++r) {
            int s = tid + r * 256;
            GLL16(A + abase + (long)(srow + r * 64) * K + kt + scol, As + s * 8);
            GLL16(B + bbase + (long)(srow + r * 64) * K + kt + scol, Bs + s * 8);
        }
        __syncthreads();
        bf16x8 af[4], bfr[4];
#pragma unroll
        for (int mf = 0; mf < 4; ++mf)
            af[mf] = *(const bf16x8*)(As + (wm + mf * 16 + li) * 32 + g * 8);
#pragma unroll
        for (int nf = 0; nf < 4; ++nf)
            bfr[nf] = *(const bf16x8*)(Bs + (wn + nf * 16 + li) * 32 + g * 8);
#pragma unroll
        for (int mf = 0; mf < 4; ++mf)
#pragma unroll
            for (int nf = 0; nf < 4; ++nf)
                acc[mf][nf] = __builtin_amdgcn_mfma_f32_16x16x32_bf16(af[mf], bfr[nf], acc[mf][nf], 0, 0, 0);
        __syncthreads();
    }

#pragma unroll
    for (int nf = 0; nf < 4; ++nf) {
        int col = bn * 128 + wn + nf * 16 + li;
        float bv = bias[col];
#pragma unroll
        for (int mf = 0; mf < 4; ++mf) {
#pragma unroll
            for (int i = 0; i < 4; ++i) {
                int row = bm * 128 + wm + mf * 16 + g * 4 + i;
                float v = acc[mf][nf][i] + bv;
                if (RELU) v = fmaxf(v, 0.f);
                if (OBF) Cb[(long)row * N + col] = f2b(v);
                else     Cf[(long)row * N + col] = v;
            }
        }
    }
}

// ---------------- attention ----------------
// grid (18 qblocks, 16 heads, 2 batch); 4 waves, each owns 32 q-rows.
// All rows attend keys [0,2048); short rows (>=2048) also attend self (epilogue).
__global__ __launch_bounds__(256, 2) void k_attn(const unsigned short* __restrict__ qkv,
                                                 unsigned short* __restrict__ ctx) {
    __shared__ unsigned short Ks[64 * 64];      // [t][d-slot swizzled]
    __shared__ unsigned short Vt[64 * 72];      // [d][t], pad 72
    __shared__ unsigned short Ps[4][32 * 64];   // per-wave P, slot-swizzled

    const int tid  = threadIdx.x;
    const int lane = tid & 63, wave = tid >> 6;
    const int g = lane >> 4, li = lane & 15;
    const int bq = blockIdx.x, h = blockIdx.y, b = blockIdx.z;
    const int q0 = bq * 128 + wave * 32;

    const long baseQ = ((long)b * S_TOT) * D3 + h * 64;
    const long baseK = baseQ + 1024;
    const long baseV = baseQ + 2048;

    // Q fragments in registers (reused across all key tiles)
    bf16x8 qf[2][2];
#pragma unroll
    for (int mf = 0; mf < 2; ++mf)
#pragma unroll
        for (int kk = 0; kk < 2; ++kk)
            qf[mf][kk] = *(const bf16x8*)(qkv + baseQ + (long)(q0 + mf * 16 + li) * D3 + kk * 32 + g * 8);

    f32x4 O[2][4] = {};
    float mrow[2][4], lrow[2][4];
#pragma unroll
    for (int mf = 0; mf < 2; ++mf)
#pragma unroll
        for (int i = 0; i < 4; ++i) { mrow[mf][i] = -1e30f; lrow[mf][i] = 0.f; }

    unsigned short* Pw = Ps[wave];

    for (int kt = 0; kt < NLONG; kt += 64) {
        // stage K (swizzled source so linear-dest LDS ends up conflict-free on read)
#pragma unroll
        for (int r = 0; r < 2; ++r) {
            int s = tid + r * 256;
            int t = s >> 3, si = s & 7;
            const unsigned short* gp = qkv + baseK + (long)(kt + t) * D3 + ((si ^ (t & 7)) * 8);
            GLL16(gp, Ks + s * 8);
        }
        // stage V transposed via registers: thread block t0=(tid&15)*4, d0=(tid>>4)*4
        {
            int t0 = (tid & 15) * 4, d0 = (tid >> 4) * 4;
            const unsigned short* vp = qkv + baseV + (long)(kt + t0) * D3 + d0;
            ushort4 r0 = *(const ushort4*)(vp);
            ushort4 r1 = *(const ushort4*)(vp + D3);
            ushort4 r2 = *(const ushort4*)(vp + 2 * D3);
            ushort4 r3 = *(const ushort4*)(vp + 3 * D3);
            *(ushort4*)(Vt + (d0 + 0) * 72 + t0) = make_ushort4(r0.x, r1.x, r2.x, r3.x);
            *(ushort4*)(Vt + (d0 + 1) * 72 + t0) = make_ushort4(r0.y, r1.y, r2.y, r3.y);
            *(ushort4*)(Vt + (d0 + 2) * 72 + t0) = make_ushort4(r0.z, r1.z, r2.z, r3.z);
            *(ushort4*)(Vt + (d0 + 3) * 72 + t0) = make_ushort4(r0.w, r1.w, r2.w, r3.w);
        }
        __syncthreads();

        // S = Q @ K^T
        f32x4 sc[2][4] = {};
#pragma unroll
        for (int kk = 0; kk < 2; ++kk) {
            bf16x8 kf[4];
#pragma unroll
            for (int nf = 0; nf < 4; ++nf) {
                int t = nf * 16 + li;
                int slot = (kk * 4 + g) ^ (t & 7);
                kf[nf] = *(const bf16x8*)(Ks + t * 64 + slot * 8);
            }
#pragma unroll
            for (int mf = 0; mf < 2; ++mf)
#pragma unroll
                for (int nf = 0; nf < 4; ++nf)
                    sc[mf][nf] = __builtin_amdgcn_mfma_f32_16x16x32_bf16(qf[mf][kk], kf[nf], sc[mf][nf], 0, 0, 0);
        }

        // online softmax (wave-parallel row reduce over 16 lanes)
#pragma unroll
        for (int mf = 0; mf < 2; ++mf) {
#pragma unroll
            for (int i = 0; i < 4; ++i) {
                float sv0 = sc[mf][0][i] * 0.125f;
                float sv1 = sc[mf][1][i] * 0.125f;
                float sv2 = sc[mf][2][i] * 0.125f;
                float sv3 = sc[mf][3][i] * 0.125f;
                float mx = fmaxf(fmaxf(sv0, sv1), fmaxf(sv2, sv3));
#pragma unroll
                for (int off = 1; off < 16; off <<= 1) mx = fmaxf(mx, __shfl_xor(mx, off));
                float mold = mrow[mf][i];
                float mnew = fmaxf(mold, mx);
                float alpha = __expf(mold - mnew);
                mrow[mf][i] = mnew;
                float p0 = __expf(sv0 - mnew);
                float p1 = __expf(sv1 - mnew);
                float p2 = __expf(sv2 - mnew);
                float p3 = __expf(sv3 - mnew);
                float ps = p0 + p1 + p2 + p3;
#pragma unroll
                for (int off = 1; off < 16; off <<= 1) ps += __shfl_xor(ps, off);
                lrow[mf][i] = lrow[mf][i] * alpha + ps;
#pragma unroll
                for (int nfd = 0; nfd < 4; ++nfd) O[mf][nfd][i] *= alpha;
                int row = mf * 16 + g * 4 + i;
                int rsw = (row & 7);
                int c0 = 0 * 16 + li, c1 = 1 * 16 + li, c2 = 2 * 16 + li, c3 = 3 * 16 + li;
                Pw[row * 64 + (((c0 >> 3) ^ rsw) * 8 + (c0 & 7))] = f2b(p0);
                Pw[row * 64 + (((c1 >> 3) ^ rsw) * 8 + (c1 & 7))] = f2b(p1);
                Pw[row * 64 + (((c2 >> 3) ^ rsw) * 8 + (c2 & 7))] = f2b(p2);
                Pw[row * 64 + (((c3 >> 3) ^ rsw) * 8 + (c3 & 7))] = f2b(p3);
            }
        }

        // O += P @ V
#pragma unroll
        for (int kk = 0; kk < 2; ++kk) {
            bf16x8 pf[2], vf[4];
#pragma unroll
            for (int mf = 0; mf < 2; ++mf) {
                int row = mf * 16 + li;
                int slot = (kk * 4 + g) ^ (row & 7);
                pf[mf] = *(const bf16x8*)(Pw + row * 64 + slot * 8);
            }
#pragma unroll
            for (int nfd = 0; nfd < 4; ++nfd) {
                int d = nfd * 16 + li;
                vf[nfd] = *(const bf16x8*)(Vt + d * 72 + kk * 32 + g * 8);
            }
#pragma unroll
            for (int mf = 0; mf < 2; ++mf)
#pragma unroll
                for (int nfd = 0; nfd < 4; ++nfd)
                    O[mf][nfd] = __builtin_amdgcn_mfma_f32_16x16x32_bf16(pf[mf], vf[nfd], O[mf][nfd], 0, 0, 0);
        }
        __syncthreads();
    }

    // diagonal term for short rows (q >= 2048)
    if (q0 >= NLONG) {
#pragma unroll
        for (int mf = 0; mf < 2; ++mf) {
#pragma unroll
            for (int i = 0; i < 4; ++i) {
                int q = q0 + mf * 16 + g * 4 + i;
                ushort4 q4 = *(const ushort4*)(qkv + baseQ + (long)q * D3 + li * 4);
                ushort4 k4 = *(const ushort4*)(qkv + baseK + (long)q * D3 + li * 4);
                float p = b2f(q4.x) * b2f(k4.x) + b2f(q4.y) * b2f(k4.y) +
                          b2f(q4.z) * b2f(k4.z) + b2f(q4.w) * b2f(k4.w);
#pragma unroll
                for (int off = 1; off < 16; off <<= 1) p += __shfl_xor(p, off);
                float sd = p * 0.125f;
                float mold = mrow[mf][i];
                float mnew = fmaxf(mold, sd);
                float alpha = __expf(mold - mnew);
                float pe = __expf(sd - mnew);
                mrow[mf][i] = mnew;
                lrow[mf][i] = lrow[mf][i] * alpha + pe;
#pragma unroll
                for (int nfd = 0; nfd < 4; ++nfd) {
                    float vd = b2f(qkv[baseV + (long)q * D3 + nfd * 16 + li]);
                    O[mf][nfd][i] = O[mf][nfd][i] * alpha + pe * vd;
                }
            }
        }
    }

    // normalize + write ctx[b, q, h*64+d]
#pragma unroll
    for (int mf = 0; mf < 2; ++mf) {
#pragma unroll
        for (int i = 0; i < 4; ++i) {
            float inv = 1.0f / lrow[mf][i];
            int q = q0 + mf * 16 + g * 4 + i;
            long obase = ((long)b * S_TOT + q) * 1024 + h * 64;
#pragma unroll
            for (int nfd = 0; nfd < 4; ++nfd)
                ctx[obase + nfd * 16 + li] = f2b(O[mf][nfd][i] * inv);
        }
    }
}

// ---------------- residual + LN ----------------
DEV void block_reduce2(float& sum, float& sq, float* sbuf, int tid) {
#pragma unroll
    for (int off = 32; off > 0; off >>= 1) {
        sum += __shfl_xor(sum, off);
        sq  += __shfl_xor(sq, off);
    }
    __syncthreads();  // protect sbuf reuse across calls
    if ((tid & 63) == 0) { sbuf[(tid >> 6) * 2] = sum; sbuf[(tid >> 6) * 2 + 1] = sq; }
    __syncthreads();
    sum = sbuf[0] + sbuf[2] + sbuf[4] + sbuf[6];
    sq  = sbuf[1] + sbuf[3] + sbuf[5] + sbuf[7];
}

__global__ __launch_bounds__(256) void k_ln_resid(const float* __restrict__ xa,
                                                  const float* __restrict__ xb,
                                                  const float* __restrict__ w,
                                                  const float* __restrict__ bs,
                                                  float* __restrict__ outf,
                                                  unsigned short* __restrict__ outb) {
    __shared__ float sbuf[8];
    const int tid = threadIdx.x;
    const long base = (long)blockIdx.x * 1024 + tid * 4;
    float4 a = *(const float4*)(xa + base);
    float4 b4 = *(const float4*)(xb + base);
    float4 s = make_float4(a.x + b4.x, a.y + b4.y, a.z + b4.z, a.w + b4.w);
    float sum = s.x + s.y + s.z + s.w;
    float sq = s.x * s.x + s.y * s.y + s.z * s.z + s.w * s.w;
    block_reduce2(sum, sq, sbuf, tid);
    float mean = sum * (1.f / 1024.f);
    float var = sq * (1.f / 1024.f) - mean * mean;
    float rstd = rsqrtf(var + 1e-5f);
    float4 wv = *(const float4*)(w + tid * 4);
    float4 bv = *(const float4*)(bs + tid * 4);
    float4 o = make_float4((s.x - mean) * rstd * wv.x + bv.x,
                           (s.y - mean) * rstd * wv.y + bv.y,
                           (s.z - mean) * rstd * wv.z + bv.z,
                           (s.w - mean) * rstd * wv.w + bv.w);
    *(float4*)(outf + base) = o;
    *(ushort4*)(outb + base) = make_ushort4(f2b(o.x), f2b(o.y), f2b(o.z), f2b(o.w));
}

// y = LN(h+ff; w2,b2); x_new = LN(x+y; nw,nb)  -> outf (fp32) + outb (bf16)
__global__ __launch_bounds__(256) void k_ln_double(const float* __restrict__ h,
                                                   const float* __restrict__ ff,
                                                   const float* __restrict__ x,
                                                   const float* __restrict__ w2,
                                                   const float* __restrict__ bb2,
                                                   const float* __restrict__ nw,
                                                   const float* __restrict__ nb,
                                                   float* __restrict__ outf,
                                                   unsigned short* __restrict__ outb) {
    __shared__ float sbuf[8];
    const int tid = threadIdx.x;
    const long base = (long)blockIdx.x * 1024 + tid * 4;
    float4 hv = *(const float4*)(h + base);
    float4 fv = *(const float4*)(ff + base);
    float4 s = make_float4(hv.x + fv.x, hv.y + fv.y, hv.z + fv.z, hv.w + fv.w);
    float sum = s.x + s.y + s.z + s.w;
    float sq = s.x * s.x + s.y * s.y + s.z * s.z + s.w * s.w;
    block_reduce2(sum, sq, sbuf, tid);
    float mean = sum * (1.f / 1024.f);
    float rstd = rsqrtf(sq * (1.f / 1024.f) - mean * mean + 1e-5f);
    float4 wv = *(const float4*)(w2 + tid * 4);
    float4 bv = *(const float4*)(bb2 + tid * 4);
    float4 y = make_float4((s.x - mean) * rstd * wv.x + bv.x,
                           (s.y - mean) * rstd * wv.y + bv.y,
                           (s.z - mean) * rstd * wv.z + bv.z,
                           (s.w - mean) * rstd * wv.w + bv.w);
    float4 xv = *(const float4*)(x + base);
    float4 t = make_float4(xv.x + y.x, xv.y + y.y, xv.z + y.z, xv.w + y.w);
    sum = t.x + t.y + t.z + t.w;
    sq = t.x * t.x + t.y * t.y + t.z * t.z + t.w * t.w;
    block_reduce2(sum, sq, sbuf, tid);
    mean = sum * (1.f / 1024.f);
    rstd = rsqrtf(sq * (1.f / 1024.f) - mean * mean + 1e-5f);
    float4 nwv = *(const float4*)(nw + tid * 4);
    float4 nbv = *(const float4*)(nb + tid * 4);
    float4 o = make_float4((t.x - mean) * rstd * nwv.x + nbv.x,
                           (t.y - mean) * rstd * nwv.y + nbv.y,
                           (t.z - mean) * rstd * nwv.z + nbv.z,
                           (t.w - mean) * rstd * nwv.w + nbv.w);
    *(float4*)(outf + base) = o;
    *(ushort4*)(outb + base) = make_ushort4(f2b(o.x), f2b(o.y), f2b(o.z), f2b(o.w));
}

// ---------------- launcher ----------------
extern "C" void kernel_launch(void* const* d_in, const int* in_sizes, int n_in,
                              void* d_out, int out_size, void* d_ws, size_t ws_size,
                              hipStream_t stream) {
    (void)in_sizes; (void)n_in; (void)out_size; (void)ws_size;
    const float* x_in  = (const float*)d_in[0];
    const float* Wqkv  = (const float*)d_in[1];
    const float* bqkv  = (const float*)d_in[2];
    const float* Wo    = (const float*)d_in[3];
    const float* bo    = (const float*)d_in[4];
    const float* W1    = (const float*)d_in[5];
    const float* b1    = (const float*)d_in[6];
    const float* W2    = (const float*)d_in[7];
    const float* b2    = (const float*)d_in[8];
    const float* ln1w  = (const float*)d_in[9];
    const float* ln1b  = (const float*)d_in[10];
    const float* ln2w  = (const float*)d_in[11];
    const float* ln2b  = (const float*)d_in[12];
    const float* nw    = (const float*)d_in[13];
    const float* nb    = (const float*)d_in[14];
    float* xf = (float*)d_out;  // fp32 x lives in d_out across layers

    char* p = (char*)d_ws;
    auto alloc = [&](size_t bytes) { char* r = p; p += (bytes + 255) & ~(size_t)255; return r; };
    unsigned short* wqkv_b = (unsigned short*)alloc(12582912UL * 2);
    unsigned short* wo_b   = (unsigned short*)alloc(4194304UL * 2);
    unsigned short* w1_b   = (unsigned short*)alloc(4194304UL * 2);
    unsigned short* w2_b   = (unsigned short*)alloc(4194304UL * 2);
    unsigned short* x_b    = (unsigned short*)alloc(4718592UL * 2);
    unsigned short* qkv_b  = (unsigned short*)alloc(14155776UL * 2);
    unsigned short* ctx_b  = (unsigned short*)alloc(4718592UL * 2);
    unsigned short* h_b    = (unsigned short*)alloc(4718592UL * 2);
    unsigned short* ff1_b  = (unsigned short*)alloc(4718592UL * 2);
    float* h_f   = (float*)alloc(4718592UL * 4);
    float* tmp_f = (float*)alloc(4718592UL * 4);

    k_cast<<<4096, 256, 0, stream>>>(Wqkv, wqkv_b, 12582912L);
    k_cast<<<2048, 256, 0, stream>>>(Wo, wo_b, 4194304L);
    k_cast<<<2048, 256, 0, stream>>>(W1, w1_b, 4194304L);
    k_cast<<<2048, 256, 0, stream>>>(W2, w2_b, 4194304L);
    k_castcopy<<<2048, 256, 0, stream>>>(x_in, xf, x_b, 4718592L);

    for (int l = 0; l < 4; ++l) {
        k_gemm<1, 0><<<dim3(36, 24), 256, 0, stream>>>(x_b, wqkv_b + (size_t)l * 3145728,
                                                       bqkv + l * 3072, nullptr, qkv_b, 4608, 3072, 1024);
        k_attn<<<dim3(18, 16, 2), 256, 0, stream>>>(qkv_b, ctx_b);
        k_gemm<0, 0><<<dim3(36, 8), 256, 0, stream>>>(ctx_b, wo_b + (size_t)l * 1048576,
                                                      bo + l * 1024, tmp_f, nullptr, 4608, 1024, 1024);
        k_ln_resid<<<4608, 256, 0, stream>>>(xf, tmp_f, ln1w + l * 1024, ln1b + l * 1024, h_f, h_b);
        k_gemm<1, 1><<<dim3(36, 8), 256, 0, stream>>>(h_b, w1_b + (size_t)l * 1048576,
                                                      b1 + l * 1024, nullptr, ff1_b, 4608, 1024, 1024);
        k_gemm<0, 0><<<dim3(36, 8), 256, 0, stream>>>(ff1_b, w2_b + (size_t)l * 1048576,
                                                      b2 + l * 1024, tmp_f, nullptr, 4608, 1024, 1024);
        k_ln_double<<<4608, 256, 0, stream>>>(h_f, tmp_f, xf, ln2w + l * 1024, ln2b + l * 1024,
                                              nw, nb, xf, x_b);
    }
}

// Round 3
// 1149.134 us; speedup vs baseline: 1.1868x; 1.1868x over previous
//
#include <hip/hip_runtime.h>

#define DEV __device__ __forceinline__

typedef short bf16x8 __attribute__((ext_vector_type(8)));
typedef short bf16x4_t __attribute__((ext_vector_type(4)));
typedef float f32x4 __attribute__((ext_vector_type(4)));

#define S_TOT 2304
#define D3    3072
#define NLONG 2048

DEV unsigned short f2b(float f) {
    union { float f; unsigned u; } v; v.f = f;
    unsigned r = v.u + 0x7fffu + ((v.u >> 16) & 1u);
    return (unsigned short)(r >> 16);
}
DEV float b2f(unsigned short u) {
    union { unsigned u; float f; } v; v.u = ((unsigned)u) << 16;
    return v.f;
}

#define GLL16(g, l) __builtin_amdgcn_global_load_lds( \
    (const __attribute__((address_space(1))) void*)(g), \
    (__attribute__((address_space(3))) void*)(l), 16, 0, 0)

DEV bf16x4_t tr_read(unsigned byteaddr) {
    bf16x4_t r;
    asm volatile("ds_read_b64_tr_b16 %0, %1" : "=v"(r) : "v"(byteaddr));
    return r;
}

// ---------------- casts ----------------
__global__ __launch_bounds__(256) void k_cast(const float* __restrict__ in,
                                              unsigned short* __restrict__ out, long n) {
    long i = ((long)blockIdx.x * 256 + threadIdx.x) * 4;
    long stride = (long)gridDim.x * 1024;
    for (; i < n; i += stride) {
        float4 v = *(const float4*)(in + i);
        *(ushort4*)(out + i) = make_ushort4(f2b(v.x), f2b(v.y), f2b(v.z), f2b(v.w));
    }
}

__global__ __launch_bounds__(256) void k_castcopy(const float* __restrict__ in,
                                                  float* __restrict__ outf,
                                                  unsigned short* __restrict__ outb, long n) {
    long i = ((long)blockIdx.x * 256 + threadIdx.x) * 4;
    long stride = (long)gridDim.x * 1024;
    for (; i < n; i += stride) {
        float4 v = *(const float4*)(in + i);
        *(float4*)(outf + i) = v;
        *(ushort4*)(outb + i) = make_ushort4(f2b(v.x), f2b(v.y), f2b(v.z), f2b(v.w));
    }
}

// ---------------- GEMM: C[M,N] = A[M,K] @ B[N,K]^T + bias ----------------
// 128xBN tile, double-buffered LDS, single barrier per K-step, prefetch after barrier.
template<int BN, int OBF, int RELU>
__global__ __launch_bounds__(256, 2) void k_gemm(const unsigned short* __restrict__ A,
                                                 const unsigned short* __restrict__ B,
                                                 const float* __restrict__ bias,
                                                 float* __restrict__ Cf,
                                                 unsigned short* __restrict__ Cb,
                                                 int M, int N, int K) {
    __shared__ unsigned short As[2][128 * 32];
    __shared__ unsigned short Bs[2][BN * 32];
    const int tid  = threadIdx.x;
    const int lane = tid & 63;
    const int wave = tid >> 6;
    const int g = lane >> 4, li = lane & 15;
    const int bm = blockIdx.x, bn = blockIdx.y;
    constexpr int WN = BN / 2;
    constexpr int NF = WN / 16;
    const int wm = (wave >> 1) * 64, wn = (wave & 1) * WN;

    f32x4 acc[4][NF] = {};

    const long abase = (long)bm * 128 * K;
    const long bbase = (long)bn * BN * K;
    const int srow = tid >> 2;
    const int scol = (tid & 3) * 8;

    auto stage = [&](int kt, int buf) {
        GLL16(A + abase + (long)srow * K + kt + scol, As[buf] + tid * 8);
        GLL16(A + abase + (long)(srow + 64) * K + kt + scol, As[buf] + (tid + 256) * 8);
        GLL16(B + bbase + (long)srow * K + kt + scol, Bs[buf] + tid * 8);
        if (BN == 128)
            GLL16(B + bbase + (long)(srow + 64) * K + kt + scol, Bs[buf] + (tid + 256) * 8);
    };

    const int nt = K / 32;
    stage(0, 0);
    for (int t = 0; t < nt; ++t) {
        __syncthreads();                       // buf[t&1] staged; prior reads of buf[(t+1)&1] done
        if (t + 1 < nt) stage((t + 1) * 32, (t + 1) & 1);
        const unsigned short* Ab = As[t & 1];
        const unsigned short* Bb = Bs[t & 1];
        bf16x8 af[4], bfr[NF];
#pragma unroll
        for (int mf = 0; mf < 4; ++mf)
            af[mf] = *(const bf16x8*)(Ab + (wm + mf * 16 + li) * 32 + g * 8);
#pragma unroll
        for (int nf = 0; nf < NF; ++nf)
            bfr[nf] = *(const bf16x8*)(Bb + (wn + nf * 16 + li) * 32 + g * 8);
#pragma unroll
        for (int mf = 0; mf < 4; ++mf)
#pragma unroll
            for (int nf = 0; nf < NF; ++nf)
                acc[mf][nf] = __builtin_amdgcn_mfma_f32_16x16x32_bf16(af[mf], bfr[nf], acc[mf][nf], 0, 0, 0);
    }

#pragma unroll
    for (int nf = 0; nf < NF; ++nf) {
        int col = bn * BN + wn + nf * 16 + li;
        float bv = bias[col];
#pragma unroll
        for (int mf = 0; mf < 4; ++mf) {
#pragma unroll
            for (int i = 0; i < 4; ++i) {
                int row = bm * 128 + wm + mf * 16 + g * 4 + i;
                float v = acc[mf][nf][i] + bv;
                if (RELU) v = fmaxf(v, 0.f);
                if (OBF) Cb[(long)row * N + col] = f2b(v);
                else     Cf[(long)row * N + col] = v;
            }
        }
    }
}

// ---------------- attention ----------------
// grid (18 qblocks, 16 heads, 2 batch); 4 waves, each owns 32 q-rows.
// No-max softmax (scores bounded ~|3|), deferred row-sum, double-buffered K/V,
// P through LDS in tr-layout (cvt_pk + ds_write_b64, ds_read_b64_tr_b16 back).
__global__ __launch_bounds__(256, 2) void k_attn(const unsigned short* __restrict__ qkv,
                                                 unsigned short* __restrict__ ctx) {
    __shared__ unsigned short Ks[2][64 * 64];
    __shared__ unsigned short Vt[2][64 * 72];
    __shared__ unsigned short Ps[4][2048];

    const int tid  = threadIdx.x;
    const int lane = tid & 63, wave = tid >> 6;
    const int g = lane >> 4, li = lane & 15;
    const int bq = blockIdx.x, h = blockIdx.y, b = blockIdx.z;
    const int q0 = bq * 128 + wave * 32;

    const long baseQ = ((long)b * S_TOT) * D3 + h * 64;
    const long baseK = baseQ + 1024;
    const long baseV = baseQ + 2048;

    bf16x8 qf[2][2];
#pragma unroll
    for (int mf = 0; mf < 2; ++mf)
#pragma unroll
        for (int kk = 0; kk < 2; ++kk)
            qf[mf][kk] = *(const bf16x8*)(qkv + baseQ + (long)(q0 + mf * 16 + li) * D3 + kk * 32 + g * 8);

    f32x4 O[2][4] = {};
    float psum[2][4] = {};

    unsigned short* Pw = Ps[wave];
    const unsigned pwb = (unsigned)(size_t)Pw + lane * 8u;  // tr-read per-lane base

    auto stageK = [&](int kt, int buf) {
#pragma unroll
        for (int r = 0; r < 2; ++r) {
            int s = tid + r * 256;
            int kr = s >> 3, si = s & 7;
            GLL16(qkv + baseK + (long)(kt + kr) * D3 + ((si ^ (kr & 7)) * 8), Ks[buf] + s * 8);
        }
    };
    auto loadV = [&](int kt, ushort4* vr) {
        int t0 = (tid & 15) * 4, d0 = (tid >> 4) * 4;
        const unsigned short* vp = qkv + baseV + (long)(kt + t0) * D3 + d0;
        vr[0] = *(const ushort4*)(vp);
        vr[1] = *(const ushort4*)(vp + D3);
        vr[2] = *(const ushort4*)(vp + 2 * D3);
        vr[3] = *(const ushort4*)(vp + 3 * D3);
    };
    auto writeVt = [&](const ushort4* vr, int buf) {
        int t0 = (tid & 15) * 4, d0 = (tid >> 4) * 4;
        unsigned short* Vb = Vt[buf];
        *(ushort4*)(Vb + (d0 + 0) * 72 + t0) = make_ushort4(vr[0].x, vr[1].x, vr[2].x, vr[3].x);
        *(ushort4*)(Vb + (d0 + 1) * 72 + t0) = make_ushort4(vr[0].y, vr[1].y, vr[2].y, vr[3].y);
        *(ushort4*)(Vb + (d0 + 2) * 72 + t0) = make_ushort4(vr[0].z, vr[1].z, vr[2].z, vr[3].z);
        *(ushort4*)(Vb + (d0 + 3) * 72 + t0) = make_ushort4(vr[0].w, vr[1].w, vr[2].w, vr[3].w);
    };

    auto compute = [&](int cur) {
        // --- S = Q @ K^T ---
        f32x4 sc[2][4] = {};
        const unsigned short* Kb = Ks[cur];
#pragma unroll
        for (int kk = 0; kk < 2; ++kk) {
            bf16x8 kf[4];
#pragma unroll
            for (int nf = 0; nf < 4; ++nf) {
                int kr = nf * 16 + li;
                int slot = (kk * 4 + g) ^ (kr & 7);
                kf[nf] = *(const bf16x8*)(Kb + kr * 64 + slot * 8);
            }
#pragma unroll
            for (int mf = 0; mf < 2; ++mf)
#pragma unroll
                for (int nf = 0; nf < 4; ++nf)
                    sc[mf][nf] = __builtin_amdgcn_mfma_f32_16x16x32_bf16(qf[mf][kk], kf[nf], sc[mf][nf], 0, 0, 0);
        }
        // --- P = exp(S/8), deferred sum, store in tr-layout ---
#pragma unroll
        for (int mf = 0; mf < 2; ++mf) {
#pragma unroll
            for (int nf = 0; nf < 4; ++nf) {
                float p0 = __expf(sc[mf][nf][0] * 0.125f);
                float p1 = __expf(sc[mf][nf][1] * 0.125f);
                float p2 = __expf(sc[mf][nf][2] * 0.125f);
                float p3 = __expf(sc[mf][nf][3] * 0.125f);
                psum[mf][0] += p0; psum[mf][1] += p1;
                psum[mf][2] += p2; psum[mf][3] += p3;
                unsigned lo, hi;
                asm("v_cvt_pk_bf16_f32 %0, %1, %2" : "=v"(lo) : "v"(p0), "v"(p1));
                asm("v_cvt_pk_bf16_f32 %0, %1, %2" : "=v"(hi) : "v"(p2), "v"(p3));
                // storage elem idx: row16 + (k&3)*16 + (k>>3)*64 + ((k>>2)&1)*512 + mf*1024
                unsigned idx = (unsigned)(g * 4 + (li & 3) * 16 + (nf * 2 + (li >> 3)) * 64 +
                                          ((li >> 2) & 1) * 512 + mf * 1024);
                *(uint2*)(Pw + idx) = make_uint2(lo, hi);
            }
        }
        asm volatile("" ::: "memory");   // keep P stores before tr reads
        bf16x4_t pa[2][2][2];
#pragma unroll
        for (int mf = 0; mf < 2; ++mf)
#pragma unroll
            for (int kk = 0; kk < 2; ++kk) {
                unsigned base = pwb + 2u * (unsigned)(kk * 256 + mf * 1024);
                pa[mf][kk][0] = tr_read(base);
                pa[mf][kk][1] = tr_read(base + 1024u);
            }
        asm volatile("s_waitcnt lgkmcnt(0)" ::: "memory");
        __builtin_amdgcn_sched_barrier(0);
        // --- O += P @ V ---
        const unsigned short* Vb = Vt[cur];
#pragma unroll
        for (int kk = 0; kk < 2; ++kk) {
            bf16x8 vf[4];
#pragma unroll
            for (int nfd = 0; nfd < 4; ++nfd)
                vf[nfd] = *(const bf16x8*)(Vb + (nfd * 16 + li) * 72 + kk * 32 + g * 8);
#pragma unroll
            for (int mf = 0; mf < 2; ++mf) {
                bf16x8 paf = __builtin_shufflevector(pa[mf][kk][0], pa[mf][kk][1],
                                                     0, 1, 2, 3, 4, 5, 6, 7);
#pragma unroll
                for (int nfd = 0; nfd < 4; ++nfd)
                    O[mf][nfd] = __builtin_amdgcn_mfma_f32_16x16x32_bf16(paf, vf[nfd], O[mf][nfd], 0, 0, 0);
            }
        }
    };

    ushort4 vrA[4], vrB[4];
    stageK(0, 0);
    loadV(0, vrA);
    for (int ti = 0; ti < 32; ti += 2) {
        writeVt(vrA, 0);
        __syncthreads();
        if (ti + 1 < 32) { stageK((ti + 1) * 64, 1); loadV((ti + 1) * 64, vrB); }
        compute(0);
        writeVt(vrB, 1);
        __syncthreads();
        if (ti + 2 < 32) { stageK((ti + 2) * 64, 0); loadV((ti + 2) * 64, vrA); }
        compute(1);
    }

    // row sums (one reduction at the end)
    float lrow[2][4];
#pragma unroll
    for (int mf = 0; mf < 2; ++mf)
#pragma unroll
        for (int i = 0; i < 4; ++i) {
            float s = psum[mf][i];
#pragma unroll
            for (int off = 1; off < 16; off <<= 1) s += __shfl_xor(s, off);
            lrow[mf][i] = s;
        }

    // diagonal term for short rows (q >= 2048)
    if (q0 >= NLONG) {
#pragma unroll
        for (int mf = 0; mf < 2; ++mf) {
#pragma unroll
            for (int i = 0; i < 4; ++i) {
                int q = q0 + mf * 16 + g * 4 + i;
                ushort4 q4 = *(const ushort4*)(qkv + baseQ + (long)q * D3 + li * 4);
                ushort4 k4 = *(const ushort4*)(qkv + baseK + (long)q * D3 + li * 4);
                float p = b2f(q4.x) * b2f(k4.x) + b2f(q4.y) * b2f(k4.y) +
                          b2f(q4.z) * b2f(k4.z) + b2f(q4.w) * b2f(k4.w);
#pragma unroll
                for (int off = 1; off < 16; off <<= 1) p += __shfl_xor(p, off);
                float pe = __expf(p * 0.125f);
                lrow[mf][i] += pe;
#pragma unroll
                for (int nfd = 0; nfd < 4; ++nfd) {
                    float vd = b2f(qkv[baseV + (long)q * D3 + nfd * 16 + li]);
                    O[mf][nfd][i] += pe * vd;
                }
            }
        }
    }

#pragma unroll
    for (int mf = 0; mf < 2; ++mf) {
#pragma unroll
        for (int i = 0; i < 4; ++i) {
            float inv = 1.0f / lrow[mf][i];
            int q = q0 + mf * 16 + g * 4 + i;
            long obase = ((long)b * S_TOT + q) * 1024 + h * 64;
#pragma unroll
            for (int nfd = 0; nfd < 4; ++nfd)
                ctx[obase + nfd * 16 + li] = f2b(O[mf][nfd][i] * inv);
        }
    }
}

// ---------------- residual + LN ----------------
DEV void block_reduce2(float& sum, float& sq, float* sbuf, int tid) {
#pragma unroll
    for (int off = 32; off > 0; off >>= 1) {
        sum += __shfl_xor(sum, off);
        sq  += __shfl_xor(sq, off);
    }
    __syncthreads();
    if ((tid & 63) == 0) { sbuf[(tid >> 6) * 2] = sum; sbuf[(tid >> 6) * 2 + 1] = sq; }
    __syncthreads();
    sum = sbuf[0] + sbuf[2] + sbuf[4] + sbuf[6];
    sq  = sbuf[1] + sbuf[3] + sbuf[5] + sbuf[7];
}

__global__ __launch_bounds__(256) void k_ln_resid(const float* __restrict__ xa,
                                                  const float* __restrict__ xb,
                                                  const float* __restrict__ w,
                                                  const float* __restrict__ bs,
                                                  float* __restrict__ outf,
                                                  unsigned short* __restrict__ outb) {
    __shared__ float sbuf[8];
    const int tid = threadIdx.x;
    const long base = (long)blockIdx.x * 1024 + tid * 4;
    float4 a = *(const float4*)(xa + base);
    float4 b4 = *(const float4*)(xb + base);
    float4 s = make_float4(a.x + b4.x, a.y + b4.y, a.z + b4.z, a.w + b4.w);
    float sum = s.x + s.y + s.z + s.w;
    float sq = s.x * s.x + s.y * s.y + s.z * s.z + s.w * s.w;
    block_reduce2(sum, sq, sbuf, tid);
    float mean = sum * (1.f / 1024.f);
    float rstd = rsqrtf(sq * (1.f / 1024.f) - mean * mean + 1e-5f);
    float4 wv = *(const float4*)(w + tid * 4);
    float4 bv = *(const float4*)(bs + tid * 4);
    float4 o = make_float4((s.x - mean) * rstd * wv.x + bv.x,
                           (s.y - mean) * rstd * wv.y + bv.y,
                           (s.z - mean) * rstd * wv.z + bv.z,
                           (s.w - mean) * rstd * wv.w + bv.w);
    *(float4*)(outf + base) = o;
    *(ushort4*)(outb + base) = make_ushort4(f2b(o.x), f2b(o.y), f2b(o.z), f2b(o.w));
}

__global__ __launch_bounds__(256) void k_ln_double(const float* __restrict__ h,
                                                   const float* __restrict__ ff,
                                                   const float* __restrict__ x,
                                                   const float* __restrict__ w2,
                                                   const float* __restrict__ bb2,
                                                   const float* __restrict__ nw,
                                                   const float* __restrict__ nb,
                                                   float* __restrict__ outf,
                                                   unsigned short* __restrict__ outb) {
    __shared__ float sbuf[8];
    const int tid = threadIdx.x;
    const long base = (long)blockIdx.x * 1024 + tid * 4;
    float4 hv = *(const float4*)(h + base);
    float4 fv = *(const float4*)(ff + base);
    float4 s = make_float4(hv.x + fv.x, hv.y + fv.y, hv.z + fv.z, hv.w + fv.w);
    float sum = s.x + s.y + s.z + s.w;
    float sq = s.x * s.x + s.y * s.y + s.z * s.z + s.w * s.w;
    block_reduce2(sum, sq, sbuf, tid);
    float mean = sum * (1.f / 1024.f);
    float rstd = rsqrtf(sq * (1.f / 1024.f) - mean * mean + 1e-5f);
    float4 wv = *(const float4*)(w2 + tid * 4);
    float4 bv = *(const float4*)(bb2 + tid * 4);
    float4 y = make_float4((s.x - mean) * rstd * wv.x + bv.x,
                           (s.y - mean) * rstd * wv.y + bv.y,
                           (s.z - mean) * rstd * wv.z + bv.z,
                           (s.w - mean) * rstd * wv.w + bv.w);
    float4 xv = *(const float4*)(x + base);
    float4 t = make_float4(xv.x + y.x, xv.y + y.y, xv.z + y.z, xv.w + y.w);
    sum = t.x + t.y + t.z + t.w;
    sq = t.x * t.x + t.y * t.y + t.z * t.z + t.w * t.w;
    block_reduce2(sum, sq, sbuf, tid);
    mean = sum * (1.f / 1024.f);
    rstd = rsqrtf(sq * (1.f / 1024.f) - mean * mean + 1e-5f);
    float4 nwv = *(const float4*)(nw + tid * 4);
    float4 nbv = *(const float4*)(nb + tid * 4);
    float4 o = make_float4((t.x - mean) * rstd * nwv.x + nbv.x,
                           (t.y - mean) * rstd * nwv.y + nbv.y,
                           (t.z - mean) * rstd * nwv.z + nbv.z,
                           (t.w - mean) * rstd * nwv.w + nbv.w);
    *(float4*)(outf + base) = o;
    *(ushort4*)(outb + base) = make_ushort4(f2b(o.x), f2b(o.y), f2b(o.z), f2b(o.w));
}

// ---------------- launcher ----------------
extern "C" void kernel_launch(void* const* d_in, const int* in_sizes, int n_in,
                              void* d_out, int out_size, void* d_ws, size_t ws_size,
                              hipStream_t stream) {
    (void)in_sizes; (void)n_in; (void)out_size; (void)ws_size;
    const float* x_in  = (const float*)d_in[0];
    const float* Wqkv  = (const float*)d_in[1];
    const float* bqkv  = (const float*)d_in[2];
    const float* Wo    = (const float*)d_in[3];
    const float* bo    = (const float*)d_in[4];
    const float* W1    = (const float*)d_in[5];
    const float* b1    = (const float*)d_in[6];
    const float* W2    = (const float*)d_in[7];
    const float* b2    = (const float*)d_in[8];
    const float* ln1w  = (const float*)d_in[9];
    const float* ln1b  = (const float*)d_in[10];
    const float* ln2w  = (const float*)d_in[11];
    const float* ln2b  = (const float*)d_in[12];
    const float* nw    = (const float*)d_in[13];
    const float* nb    = (const float*)d_in[14];
    float* xf = (float*)d_out;

    char* p = (char*)d_ws;
    auto alloc = [&](size_t bytes) { char* r = p; p += (bytes + 255) & ~(size_t)255; return r; };
    unsigned short* wqkv_b = (unsigned short*)alloc(12582912UL * 2);
    unsigned short* wo_b   = (unsigned short*)alloc(4194304UL * 2);
    unsigned short* w1_b   = (unsigned short*)alloc(4194304UL * 2);
    unsigned short* w2_b   = (unsigned short*)alloc(4194304UL * 2);
    unsigned short* x_b    = (unsigned short*)alloc(4718592UL * 2);
    unsigned short* qkv_b  = (unsigned short*)alloc(14155776UL * 2);
    unsigned short* ctx_b  = (unsigned short*)alloc(4718592UL * 2);
    unsigned short* h_b    = (unsigned short*)alloc(4718592UL * 2);
    unsigned short* ff1_b  = (unsigned short*)alloc(4718592UL * 2);
    float* h_f   = (float*)alloc(4718592UL * 4);
    float* tmp_f = (float*)alloc(4718592UL * 4);

    k_cast<<<4096, 256, 0, stream>>>(Wqkv, wqkv_b, 12582912L);
    k_cast<<<2048, 256, 0, stream>>>(Wo, wo_b, 4194304L);
    k_cast<<<2048, 256, 0, stream>>>(W1, w1_b, 4194304L);
    k_cast<<<2048, 256, 0, stream>>>(W2, w2_b, 4194304L);
    k_castcopy<<<2048, 256, 0, stream>>>(x_in, xf, x_b, 4718592L);

    for (int l = 0; l < 4; ++l) {
        k_gemm<128, 1, 0><<<dim3(36, 24), 256, 0, stream>>>(x_b, wqkv_b + (size_t)l * 3145728,
                                                            bqkv + l * 3072, nullptr, qkv_b, 4608, 3072, 1024);
        k_attn<<<dim3(18, 16, 2), 256, 0, stream>>>(qkv_b, ctx_b);
        k_gemm<64, 0, 0><<<dim3(36, 16), 256, 0, stream>>>(ctx_b, wo_b + (size_t)l * 1048576,
                                                           bo + l * 1024, tmp_f, nullptr, 4608, 1024, 1024);
        k_ln_resid<<<4608, 256, 0, stream>>>(xf, tmp_f, ln1w + l * 1024, ln1b + l * 1024, h_f, h_b);
        k_gemm<64, 1, 1><<<dim3(36, 16), 256, 0, stream>>>(h_b, w1_b + (size_t)l * 1048576,
                                                           b1 + l * 1024, nullptr, ff1_b, 4608, 1024, 1024);
        k_gemm<64, 0, 0><<<dim3(36, 16), 256, 0, stream>>>(ff1_b, w2_b + (size_t)l * 1048576,
                                                           b2 + l * 1024, tmp_f, nullptr, 4608, 1024, 1024);
        k_ln_double<<<4608, 256, 0, stream>>>(h_f, tmp_f, xf, ln2w + l * 1024, ln2b + l * 1024,
                                              nw, nb, xf, x_b);
    }
}

// Round 4
// 1121.170 us; speedup vs baseline: 1.2164x; 1.0249x over previous
//
#include <hip/hip_runtime.h>

#define DEV __device__ __forceinline__

typedef short bf16x8 __attribute__((ext_vector_type(8)));
typedef short bf16x4_t __attribute__((ext_vector_type(4)));
typedef float f32x4 __attribute__((ext_vector_type(4)));

#define S_TOT 2304
#define D3    3072
#define NLONG 2048
#define OSTRIDE 4718592L   // elems per O-chunk partial (2*16*2304*64)

DEV unsigned short f2b(float f) {
    union { float f; unsigned u; } v; v.f = f;
    unsigned r = v.u + 0x7fffu + ((v.u >> 16) & 1u);
    return (unsigned short)(r >> 16);
}
DEV float b2f(unsigned short u) {
    union { unsigned u; float f; } v; v.u = ((unsigned)u) << 16;
    return v.f;
}

#define GLL16(g, l) __builtin_amdgcn_global_load_lds( \
    (const __attribute__((address_space(1))) void*)(g), \
    (__attribute__((address_space(3))) void*)(l), 16, 0, 0)

DEV bf16x4_t tr_read(unsigned byteaddr) {
    bf16x4_t r;
    asm volatile("ds_read_b64_tr_b16 %0, %1" : "=v"(r) : "v"(byteaddr));
    return r;
}

// ---------------- casts ----------------
__global__ __launch_bounds__(256) void k_cast(const float* __restrict__ in,
                                              unsigned short* __restrict__ out, long n) {
    long i = ((long)blockIdx.x * 256 + threadIdx.x) * 4;
    long stride = (long)gridDim.x * 1024;
    for (; i < n; i += stride) {
        float4 v = *(const float4*)(in + i);
        *(ushort4*)(out + i) = make_ushort4(f2b(v.x), f2b(v.y), f2b(v.z), f2b(v.w));
    }
}

__global__ __launch_bounds__(256) void k_castcopy(const float* __restrict__ in,
                                                  float* __restrict__ outf,
                                                  unsigned short* __restrict__ outb, long n) {
    long i = ((long)blockIdx.x * 256 + threadIdx.x) * 4;
    long stride = (long)gridDim.x * 1024;
    for (; i < n; i += stride) {
        float4 v = *(const float4*)(in + i);
        *(float4*)(outf + i) = v;
        *(ushort4*)(outb + i) = make_ushort4(f2b(v.x), f2b(v.y), f2b(v.z), f2b(v.w));
    }
}

// ---------------- GEMM: C[M,N] = A[M,K] @ B[N,K]^T + bias ----------------
// 128xBN tile, 3-buffer LDS, raw s_barrier + counted vmcnt (2-deep pipeline),
// XCD-aware bijective block swizzle.
template<int BN, int OBF, int RELU>
__global__ __launch_bounds__(256, BN == 128 ? 3 : 4)
void k_gemm(const unsigned short* __restrict__ A,
            const unsigned short* __restrict__ B,
            const float* __restrict__ bias,
            float* __restrict__ Cf,
            unsigned short* __restrict__ Cb,
            int M, int N, int K) {
    __shared__ unsigned short As[3][128 * 32];
    __shared__ unsigned short Bs[3][BN * 32];
    const int tid  = threadIdx.x;
    const int lane = tid & 63;
    const int wave = tid >> 6;
    const int g = lane >> 4, li = lane & 15;

    // XCD swizzle (grid counts here are multiples of 8)
    const int nbm = gridDim.x;
    const int nwg = nbm * gridDim.y;
    int id = blockIdx.x + blockIdx.y * nbm;
    if ((nwg & 7) == 0) id = (id & 7) * (nwg >> 3) + (id >> 3);
    const int bm = id % nbm, bn = id / nbm;

    constexpr int WN = BN / 2;
    constexpr int NF = WN / 16;
    const int wm = (wave >> 1) * 64, wn = (wave & 1) * WN;

    f32x4 acc[4][NF] = {};

    const long abase = (long)bm * 128 * K;
    const long bbase = (long)bn * BN * K;
    const int srow = tid >> 2;
    const int scol = (tid & 3) * 8;

    auto stage = [&](int kt, int buf) {
        GLL16(A + abase + (long)srow * K + kt + scol, As[buf] + tid * 8);
        GLL16(A + abase + (long)(srow + 64) * K + kt + scol, As[buf] + (tid + 256) * 8);
        GLL16(B + bbase + (long)srow * K + kt + scol, Bs[buf] + tid * 8);
        if (BN == 128)
            GLL16(B + bbase + (long)(srow + 64) * K + kt + scol, Bs[buf] + (tid + 256) * 8);
    };

    const int nt = K / 32;
    stage(0, 0);
    stage(32, 1);
    if constexpr (BN == 128) asm volatile("s_waitcnt vmcnt(4)" ::: "memory");
    else                     asm volatile("s_waitcnt vmcnt(3)" ::: "memory");

    for (int t = 0; t < nt; ++t) {
        __builtin_amdgcn_s_barrier();
        __builtin_amdgcn_sched_barrier(0);
        asm volatile("" ::: "memory");
        if (t + 2 < nt) stage((t + 2) * 32, (t + 2) % 3);
        const unsigned short* Ab = As[t % 3];
        const unsigned short* Bb = Bs[t % 3];
        bf16x8 af[4], bfr[NF];
#pragma unroll
        for (int mf = 0; mf < 4; ++mf)
            af[mf] = *(const bf16x8*)(Ab + (wm + mf * 16 + li) * 32 + g * 8);
#pragma unroll
        for (int nf = 0; nf < NF; ++nf)
            bfr[nf] = *(const bf16x8*)(Bb + (wn + nf * 16 + li) * 32 + g * 8);
#pragma unroll
        for (int mf = 0; mf < 4; ++mf)
#pragma unroll
            for (int nf = 0; nf < NF; ++nf)
                acc[mf][nf] = __builtin_amdgcn_mfma_f32_16x16x32_bf16(af[mf], bfr[nf], acc[mf][nf], 0, 0, 0);
        if (t + 2 < nt) {
            if constexpr (BN == 128) asm volatile("s_waitcnt vmcnt(4)" ::: "memory");
            else                     asm volatile("s_waitcnt vmcnt(3)" ::: "memory");
        } else {
            asm volatile("s_waitcnt vmcnt(0)" ::: "memory");
        }
    }

#pragma unroll
    for (int nf = 0; nf < NF; ++nf) {
        int col = bn * BN + wn + nf * 16 + li;
        float bv = bias[col];
#pragma unroll
        for (int mf = 0; mf < 4; ++mf) {
#pragma unroll
            for (int i = 0; i < 4; ++i) {
                int row = bm * 128 + wm + mf * 16 + g * 4 + i;
                float v = acc[mf][nf][i] + bv;
                if (RELU) v = fmaxf(v, 0.f);
                if (OBF) Cb[(long)row * N + col] = f2b(v);
                else     Cf[(long)row * N + col] = v;
            }
        }
    }
}

// ---------------- attention (key-split, partial accumulation) ----------------
// grid (18 qblocks, 16 heads, 4 = b*2... z: b = z&1, chunk = z>>1); 4 waves x 32 q-rows.
// Each block scans 1024 keys (chunk), writes UNNORMALIZED O (fp32) + row-sum l.
// No-max softmax => partials combine by addition in k_comb.
__global__ __launch_bounds__(256, 3) void k_attn(const unsigned short* __restrict__ qkv,
                                                 float* __restrict__ Opart,
                                                 float* __restrict__ lpart) {
    __shared__ unsigned short Ks[2][4096];
    __shared__ unsigned short Vt[2][4096];
    __shared__ unsigned short Ps[4][2048];

    const int tid  = threadIdx.x;
    const int lane = tid & 63, wave = tid >> 6;
    const int g = lane >> 4, li = lane & 15;
    const int bq = blockIdx.x, h = blockIdx.y;
    const int b = blockIdx.z & 1, chunk = blockIdx.z >> 1;
    const int q0 = bq * 128 + wave * 32;
    const int koff = chunk * 1024;

    const long baseQ = ((long)b * S_TOT) * D3 + h * 64;
    const long baseK = baseQ + 1024;
    const long baseV = baseQ + 2048;

    bf16x8 qf[2][2];
#pragma unroll
    for (int mf = 0; mf < 2; ++mf)
#pragma unroll
        for (int kk = 0; kk < 2; ++kk)
            qf[mf][kk] = *(const bf16x8*)(qkv + baseQ + (long)(q0 + mf * 16 + li) * D3 + kk * 32 + g * 8);

    f32x4 O[2][4] = {};
    float psum[2][4] = {};

    unsigned short* Pw = Ps[wave];
    const unsigned pwb = (unsigned)(size_t)Pw + lane * 8u;

    auto stage = [&](int ti, int buf) {
        const int kt = koff + ti * 64;
#pragma unroll
        for (int r = 0; r < 2; ++r) {
            int s = tid + r * 256;
            int kr = s >> 3, si = s & 7;
            GLL16(qkv + baseK + (long)(kt + kr) * D3 + ((si ^ (kr & 7)) * 8), Ks[buf] + s * 8);
        }
#pragma unroll
        for (int r = 0; r < 2; ++r) {
            int i = tid + r * 256;
            int vt = ((i >> 5) << 2) + ((i & 7) >> 1);      // key row 0..63
            int vd = (((i >> 3) & 3) << 4) + ((i & 1) << 3); // d 0..56 step 8
            GLL16(qkv + baseV + (long)(kt + vt) * D3 + vd, Vt[buf] + i * 8);
        }
    };

    auto compute = [&](int cur) {
        // --- S = Q @ K^T ---
        f32x4 sc[2][4] = {};
        const unsigned short* Kb = Ks[cur];
#pragma unroll
        for (int kk = 0; kk < 2; ++kk) {
            bf16x8 kf[4];
#pragma unroll
            for (int nf = 0; nf < 4; ++nf) {
                int kr = nf * 16 + li;
                int slot = (kk * 4 + g) ^ (kr & 7);
                kf[nf] = *(const bf16x8*)(Kb + kr * 64 + slot * 8);
            }
#pragma unroll
            for (int mf = 0; mf < 2; ++mf)
#pragma unroll
                for (int nf = 0; nf < 4; ++nf)
                    sc[mf][nf] = __builtin_amdgcn_mfma_f32_16x16x32_bf16(qf[mf][kk], kf[nf], sc[mf][nf], 0, 0, 0);
        }
        // --- P = exp(S/8), deferred sum, store in tr-layout ---
#pragma unroll
        for (int mf = 0; mf < 2; ++mf) {
#pragma unroll
            for (int nf = 0; nf < 4; ++nf) {
                float p0 = __expf(sc[mf][nf][0] * 0.125f);
                float p1 = __expf(sc[mf][nf][1] * 0.125f);
                float p2 = __expf(sc[mf][nf][2] * 0.125f);
                float p3 = __expf(sc[mf][nf][3] * 0.125f);
                psum[mf][0] += p0; psum[mf][1] += p1;
                psum[mf][2] += p2; psum[mf][3] += p3;
                unsigned lo, hi;
                asm("v_cvt_pk_bf16_f32 %0, %1, %2" : "=v"(lo) : "v"(p0), "v"(p1));
                asm("v_cvt_pk_bf16_f32 %0, %1, %2" : "=v"(hi) : "v"(p2), "v"(p3));
                unsigned idx = (unsigned)(g * 4 + (li & 3) * 16 + (nf * 2 + (li >> 3)) * 64 +
                                          ((li >> 2) & 1) * 512 + mf * 1024);
                *(uint2*)(Pw + idx) = make_uint2(lo, hi);
            }
        }
        asm volatile("" ::: "memory");
        // --- P fragments via tr_read ---
        bf16x4_t pa[2][2][2];
#pragma unroll
        for (int mf = 0; mf < 2; ++mf)
#pragma unroll
            for (int kk = 0; kk < 2; ++kk) {
                unsigned base = pwb + 2u * (unsigned)(kk * 256 + mf * 1024);
                pa[mf][kk][0] = tr_read(base);
                pa[mf][kk][1] = tr_read(base + 1024u);
            }
        // --- V fragments via tr_read (linear-GLL-staged subtile layout) ---
        const unsigned vtb = (unsigned)(size_t)(&Vt[cur][0]) + lane * 8u + (unsigned)(lane >> 4) * 896u;
        bf16x4_t vr[2][4][2];
#pragma unroll
        for (int kk = 0; kk < 2; ++kk)
#pragma unroll
            for (int nfd = 0; nfd < 4; ++nfd) {
                unsigned base = vtb + (unsigned)(kk * 4096 + nfd * 128);
                vr[kk][nfd][0] = tr_read(base);
                vr[kk][nfd][1] = tr_read(base + 512u);
            }
        asm volatile("s_waitcnt lgkmcnt(0)" ::: "memory");
        __builtin_amdgcn_sched_barrier(0);
        // --- O += P @ V ---
#pragma unroll
        for (int kk = 0; kk < 2; ++kk) {
#pragma unroll
            for (int mf = 0; mf < 2; ++mf) {
                bf16x8 paf = __builtin_shufflevector(pa[mf][kk][0], pa[mf][kk][1],
                                                     0, 1, 2, 3, 4, 5, 6, 7);
#pragma unroll
                for (int nfd = 0; nfd < 4; ++nfd) {
                    bf16x8 vf = __builtin_shufflevector(vr[kk][nfd][0], vr[kk][nfd][1],
                                                        0, 1, 2, 3, 4, 5, 6, 7);
                    O[mf][nfd] = __builtin_amdgcn_mfma_f32_16x16x32_bf16(paf, vf, O[mf][nfd], 0, 0, 0);
                }
            }
        }
    };

    stage(0, 0);
    for (int ti = 0; ti < 16; ++ti) {
        __syncthreads();
        if (ti + 1 < 16) stage(ti + 1, (ti + 1) & 1);
        compute(ti & 1);
    }

    // row sums
    float lrow[2][4];
#pragma unroll
    for (int mf = 0; mf < 2; ++mf)
#pragma unroll
        for (int i = 0; i < 4; ++i) {
            float s = psum[mf][i];
#pragma unroll
            for (int off = 1; off < 16; off <<= 1) s += __shfl_xor(s, off);
            lrow[mf][i] = s;
        }

    // write unnormalized partial O + l
    float* Od = Opart + (long)chunk * OSTRIDE;
    const long bh = ((long)b * 16 + h) * 2304;
#pragma unroll
    for (int mf = 0; mf < 2; ++mf) {
#pragma unroll
        for (int i = 0; i < 4; ++i) {
            int q = q0 + mf * 16 + g * 4 + i;
            long ob = (bh + q) * 64;
#pragma unroll
            for (int nfd = 0; nfd < 4; ++nfd)
                Od[ob + nfd * 16 + li] = O[mf][nfd][i];
            if (li == 0)
                lpart[((long)(chunk * 2 + b) * 16 + h) * 2304 + q] = lrow[mf][i];
        }
    }
}

// ---------------- combine: O = (O1+O2[+diag]) / (l1+l2[+diag]) ----------------
__global__ __launch_bounds__(256) void k_comb(const unsigned short* __restrict__ qkv,
                                              const float* __restrict__ Opart,
                                              const float* __restrict__ lpart,
                                              unsigned short* __restrict__ ctx) {
    const int q = blockIdx.x % S_TOT;
    const int b = blockIdx.x / S_TOT;
    const int tid = threadIdx.x;
    const int h = tid >> 4;
    const int d0 = (tid & 15) * 4;

    const long idx = (((long)b * 16 + h) * 2304 + q) * 64 + d0;
    float4 O1 = *(const float4*)(Opart + idx);
    float4 O2 = *(const float4*)(Opart + OSTRIDE + idx);
    float den = lpart[((long)b * 16 + h) * 2304 + q] +
                lpart[((long)(2 + b) * 16 + h) * 2304 + q];
    float4 num = make_float4(O1.x + O2.x, O1.y + O2.y, O1.z + O2.z, O1.w + O2.w);

    if (q >= NLONG) {
        const long qb = ((long)b * S_TOT + q) * D3 + h * 64 + d0;
        ushort4 qv = *(const ushort4*)(qkv + qb);
        ushort4 kv = *(const ushort4*)(qkv + qb + 1024);
        float dot = b2f(qv.x) * b2f(kv.x) + b2f(qv.y) * b2f(kv.y) +
                    b2f(qv.z) * b2f(kv.z) + b2f(qv.w) * b2f(kv.w);
#pragma unroll
        for (int off = 1; off < 16; off <<= 1) dot += __shfl_xor(dot, off);
        float pe = __expf(dot * 0.125f);
        ushort4 vv = *(const ushort4*)(qkv + qb + 2048);
        num.x += pe * b2f(vv.x); num.y += pe * b2f(vv.y);
        num.z += pe * b2f(vv.z); num.w += pe * b2f(vv.w);
        den += pe;
    }
    float inv = 1.0f / den;
    long ob = ((long)b * S_TOT + q) * 1024 + h * 64 + d0;
    *(ushort4*)(ctx + ob) = make_ushort4(f2b(num.x * inv), f2b(num.y * inv),
                                         f2b(num.z * inv), f2b(num.w * inv));
}

// ---------------- residual + LN ----------------
DEV void block_reduce2(float& sum, float& sq, float* sbuf, int tid) {
#pragma unroll
    for (int off = 32; off > 0; off >>= 1) {
        sum += __shfl_xor(sum, off);
        sq  += __shfl_xor(sq, off);
    }
    __syncthreads();
    if ((tid & 63) == 0) { sbuf[(tid >> 6) * 2] = sum; sbuf[(tid >> 6) * 2 + 1] = sq; }
    __syncthreads();
    sum = sbuf[0] + sbuf[2] + sbuf[4] + sbuf[6];
    sq  = sbuf[1] + sbuf[3] + sbuf[5] + sbuf[7];
}

__global__ __launch_bounds__(256) void k_ln_resid(const float* __restrict__ xa,
                                                  const float* __restrict__ xb,
                                                  const float* __restrict__ w,
                                                  const float* __restrict__ bs,
                                                  float* __restrict__ outf,
                                                  unsigned short* __restrict__ outb) {
    __shared__ float sbuf[8];
    const int tid = threadIdx.x;
    const long base = (long)blockIdx.x * 1024 + tid * 4;
    float4 a = *(const float4*)(xa + base);
    float4 b4 = *(const float4*)(xb + base);
    float4 s = make_float4(a.x + b4.x, a.y + b4.y, a.z + b4.z, a.w + b4.w);
    float sum = s.x + s.y + s.z + s.w;
    float sq = s.x * s.x + s.y * s.y + s.z * s.z + s.w * s.w;
    block_reduce2(sum, sq, sbuf, tid);
    float mean = sum * (1.f / 1024.f);
    float rstd = rsqrtf(sq * (1.f / 1024.f) - mean * mean + 1e-5f);
    float4 wv = *(const float4*)(w + tid * 4);
    float4 bv = *(const float4*)(bs + tid * 4);
    float4 o = make_float4((s.x - mean) * rstd * wv.x + bv.x,
                           (s.y - mean) * rstd * wv.y + bv.y,
                           (s.z - mean) * rstd * wv.z + bv.z,
                           (s.w - mean) * rstd * wv.w + bv.w);
    *(float4*)(outf + base) = o;
    *(ushort4*)(outb + base) = make_ushort4(f2b(o.x), f2b(o.y), f2b(o.z), f2b(o.w));
}

__global__ __launch_bounds__(256) void k_ln_double(const float* __restrict__ h,
                                                   const float* __restrict__ ff,
                                                   const float* __restrict__ x,
                                                   const float* __restrict__ w2,
                                                   const float* __restrict__ bb2,
                                                   const float* __restrict__ nw,
                                                   const float* __restrict__ nb,
                                                   float* __restrict__ outf,
                                                   unsigned short* __restrict__ outb) {
    __shared__ float sbuf[8];
    const int tid = threadIdx.x;
    const long base = (long)blockIdx.x * 1024 + tid * 4;
    float4 hv = *(const float4*)(h + base);
    float4 fv = *(const float4*)(ff + base);
    float4 s = make_float4(hv.x + fv.x, hv.y + fv.y, hv.z + fv.z, hv.w + fv.w);
    float sum = s.x + s.y + s.z + s.w;
    float sq = s.x * s.x + s.y * s.y + s.z * s.z + s.w * s.w;
    block_reduce2(sum, sq, sbuf, tid);
    float mean = sum * (1.f / 1024.f);
    float rstd = rsqrtf(sq * (1.f / 1024.f) - mean * mean + 1e-5f);
    float4 wv = *(const float4*)(w2 + tid * 4);
    float4 bv = *(const float4*)(bb2 + tid * 4);
    float4 y = make_float4((s.x - mean) * rstd * wv.x + bv.x,
                           (s.y - mean) * rstd * wv.y + bv.y,
                           (s.z - mean) * rstd * wv.z + bv.z,
                           (s.w - mean) * rstd * wv.w + bv.w);
    float4 xv = *(const float4*)(x + base);
    float4 t = make_float4(xv.x + y.x, xv.y + y.y, xv.z + y.z, xv.w + y.w);
    sum = t.x + t.y + t.z + t.w;
    sq = t.x * t.x + t.y * t.y + t.z * t.z + t.w * t.w;
    block_reduce2(sum, sq, sbuf, tid);
    mean = sum * (1.f / 1024.f);
    rstd = rsqrtf(sq * (1.f / 1024.f) - mean * mean + 1e-5f);
    float4 nwv = *(const float4*)(nw + tid * 4);
    float4 nbv = *(const float4*)(nb + tid * 4);
    float4 o = make_float4((t.x - mean) * rstd * nwv.x + nbv.x,
                           (t.y - mean) * rstd * nwv.y + nbv.y,
                           (t.z - mean) * rstd * nwv.z + nbv.z,
                           (t.w - mean) * rstd * nwv.w + nbv.w);
    *(float4*)(outf + base) = o;
    *(ushort4*)(outb + base) = make_ushort4(f2b(o.x), f2b(o.y), f2b(o.z), f2b(o.w));
}

// ---------------- launcher ----------------
extern "C" void kernel_launch(void* const* d_in, const int* in_sizes, int n_in,
                              void* d_out, int out_size, void* d_ws, size_t ws_size,
                              hipStream_t stream) {
    (void)in_sizes; (void)n_in; (void)out_size; (void)ws_size;
    const float* x_in  = (const float*)d_in[0];
    const float* Wqkv  = (const float*)d_in[1];
    const float* bqkv  = (const float*)d_in[2];
    const float* Wo    = (const float*)d_in[3];
    const float* bo    = (const float*)d_in[4];
    const float* W1    = (const float*)d_in[5];
    const float* b1    = (const float*)d_in[6];
    const float* W2    = (const float*)d_in[7];
    const float* b2    = (const float*)d_in[8];
    const float* ln1w  = (const float*)d_in[9];
    const float* ln1b  = (const float*)d_in[10];
    const float* ln2w  = (const float*)d_in[11];
    const float* ln2b  = (const float*)d_in[12];
    const float* nw    = (const float*)d_in[13];
    const float* nb    = (const float*)d_in[14];
    float* xf = (float*)d_out;

    char* p = (char*)d_ws;
    auto alloc = [&](size_t bytes) { char* r = p; p += (bytes + 255) & ~(size_t)255; return r; };
    unsigned short* wqkv_b = (unsigned short*)alloc(12582912UL * 2);
    unsigned short* wo_b   = (unsigned short*)alloc(4194304UL * 2);
    unsigned short* w1_b   = (unsigned short*)alloc(4194304UL * 2);
    unsigned short* w2_b   = (unsigned short*)alloc(4194304UL * 2);
    unsigned short* x_b    = (unsigned short*)alloc(4718592UL * 2);
    unsigned short* qkv_b  = (unsigned short*)alloc(14155776UL * 2);
    unsigned short* ctx_b  = (unsigned short*)alloc(4718592UL * 2);
    unsigned short* h_b    = (unsigned short*)alloc(4718592UL * 2);
    unsigned short* ff1_b  = (unsigned short*)alloc(4718592UL * 2);
    // merged fp32 region: [0, OSTRIDE) = h_f / attn chunk0 partial,
    //                     [OSTRIDE, 2*OSTRIDE) = tmp_f / attn chunk1 partial
    float* of_f  = (float*)alloc(2 * 4718592UL * 4);
    float* h_f   = of_f;
    float* tmp_f = of_f + OSTRIDE;
    float* lpart = (float*)alloc(147456UL * 4);

    k_cast<<<4096, 256, 0, stream>>>(Wqkv, wqkv_b, 12582912L);
    k_cast<<<2048, 256, 0, stream>>>(Wo, wo_b, 4194304L);
    k_cast<<<2048, 256, 0, stream>>>(W1, w1_b, 4194304L);
    k_cast<<<2048, 256, 0, stream>>>(W2, w2_b, 4194304L);
    k_castcopy<<<2048, 256, 0, stream>>>(x_in, xf, x_b, 4718592L);

    for (int l = 0; l < 4; ++l) {
        k_gemm<128, 1, 0><<<dim3(36, 24), 256, 0, stream>>>(x_b, wqkv_b + (size_t)l * 3145728,
                                                            bqkv + l * 3072, nullptr, qkv_b, 4608, 3072, 1024);
        k_attn<<<dim3(18, 16, 4), 256, 0, stream>>>(qkv_b, of_f, lpart);
        k_comb<<<4608, 256, 0, stream>>>(qkv_b, of_f, lpart, ctx_b);
        k_gemm<64, 0, 0><<<dim3(36, 16), 256, 0, stream>>>(ctx_b, wo_b + (size_t)l * 1048576,
                                                           bo + l * 1024, tmp_f, nullptr, 4608, 1024, 1024);
        k_ln_resid<<<4608, 256, 0, stream>>>(xf, tmp_f, ln1w + l * 1024, ln1b + l * 1024, h_f, h_b);
        k_gemm<64, 1, 1><<<dim3(36, 16), 256, 0, stream>>>(h_b, w1_b + (size_t)l * 1048576,
                                                           b1 + l * 1024, nullptr, ff1_b, 4608, 1024, 1024);
        k_gemm<64, 0, 0><<<dim3(36, 16), 256, 0, stream>>>(ff1_b, w2_b + (size_t)l * 1048576,
                                                           b2 + l * 1024, tmp_f, nullptr, 4608, 1024, 1024);
        k_ln_double<<<4608, 256, 0, stream>>>(h_f, tmp_f, xf, ln2w + l * 1024, ln2b + l * 1024,
                                              nw, nb, xf, x_b);
    }
}